// Round 3
// baseline (468.584 us; speedup 1.0000x reference)
//
#include <hip/hip_runtime.h>
#include <hip/hip_bf16.h>

#define B 128
#define N 2048
#define E 16384
#define F 32
#define H 64
#define OUTD 16
#define CAP 16

typedef __attribute__((ext_vector_type(8))) short bf16x8;
typedef __attribute__((ext_vector_type(4))) float f32x4;

__device__ __forceinline__ float b2f(unsigned short u) {
    return __uint_as_float(((unsigned int)u) << 16);
}
__device__ __forceinline__ unsigned short f2b(float f) {
    unsigned int x = __float_as_uint(f);
    unsigned int r = (x + 0x7FFFu + ((x >> 16) & 1u)) >> 16;  // RNE, finite
    return (unsigned short)r;
}
__device__ __forceinline__ unsigned int pack2(float a, float b) {
    return (unsigned int)f2b(a) | ((unsigned int)f2b(b) << 16);
}

// a += unpack(u) * w   (8 bf16 values in 4 packed uints)
__device__ __forceinline__ void fma8(float (&a)[8], uint4 u, float w) {
    a[0] = fmaf(__uint_as_float(u.x << 16), w, a[0]);
    a[1] = fmaf(__uint_as_float(u.x & 0xffff0000u), w, a[1]);
    a[2] = fmaf(__uint_as_float(u.y << 16), w, a[2]);
    a[3] = fmaf(__uint_as_float(u.y & 0xffff0000u), w, a[3]);
    a[4] = fmaf(__uint_as_float(u.z << 16), w, a[4]);
    a[5] = fmaf(__uint_as_float(u.z & 0xffff0000u), w, a[5]);
    a[6] = fmaf(__uint_as_float(u.w << 16), w, a[6]);
    a[7] = fmaf(__uint_as_float(u.w & 0xffff0000u), w, a[7]);
}
__device__ __forceinline__ void add8(float (&a)[8], uint4 u) {
    a[0] += __uint_as_float(u.x << 16);
    a[1] += __uint_as_float(u.x & 0xffff0000u);
    a[2] += __uint_as_float(u.y << 16);
    a[3] += __uint_as_float(u.y & 0xffff0000u);
    a[4] += __uint_as_float(u.z << 16);
    a[5] += __uint_as_float(u.z & 0xffff0000u);
    a[6] += __uint_as_float(u.w << 16);
    a[7] += __uint_as_float(u.w & 0xffff0000u);
}

struct PrepArgs {
    const void* src[9];
    void* dst[9];
};

// ---------------------------------------------------------------------------
// K1: fused build. One block of 1024 threads per batch:
//   - probe x dtype (every block; block 0 publishes flags[0])
//   - mask count -> n
//   - SINGLE edge pass: CSR fill + degree (atomicAdd final value = full deg)
//   - dis/degc; n_arr/ovf_cnt/done; pooled=0
//   - if x is f32: cast batch rows -> packed-bf16 y image (bf16 x: y == x)
//   - blocks 1..8: weight prep (W1T/W2T bf16 images, f32 copies of rest)
// ---------------------------------------------------------------------------
__global__ __launch_bounds__(1024) void k_build(
    const void* __restrict__ x, const int* __restrict__ eidx,
    const void* __restrict__ mask, PrepArgs pa, int* __restrict__ flags,
    int* __restrict__ n_arr, float* __restrict__ dis,
    unsigned char* __restrict__ degc, unsigned short* __restrict__ ssrc,
    int2* __restrict__ ovf, int* __restrict__ ovf_cnt,
    float* __restrict__ pooled, int* __restrict__ done,
    unsigned int* __restrict__ y_u) {
    __shared__ int s_cnt[N];
    __shared__ float s_fred[16];
    __shared__ int s_w[16];
    __shared__ int s_n, s_ovf, s_xbf, s_pf;
    const int b = blockIdx.x;
    const int t = threadIdx.x;
    const int bN = b * N;
    // --- probe x dtype (first 1024 bf16-interpreted elems) ---
    {
        const unsigned short* p = (const unsigned short*)x;
        float s = (t < 1024) ? fminf(fabsf(b2f(p[t])), 1e6f) : 0.f;
        for (int o = 32; o > 0; o >>= 1) s += __shfl_down(s, o);
        if ((t & 63) == 0) s_fred[t >> 6] = s;
        __syncthreads();
        if (t == 0) {
            float a = 0.f;
            for (int i = 0; i < 16; i++) a += s_fred[i];
            int f = (a < 100.0f * 1024.0f) ? 1 : 0;
            s_xbf = f;
            if (b == 0) flags[0] = f;
        }
    }
    // --- mask mode + count ---
    const unsigned char* mb = (const unsigned char*)mask;
    int mode;
    if (mb[0] == 0x80 && mb[1] == 0x3F) mode = 2;        // bf16
    else if (mb[0] != 0 && mb[1] != 0) mode = 0;         // bytes
    else if (mb[0] != 0) mode = (mb[4] != 0) ? 1 : 4;    // int32 : int64
    else mode = 3;                                       // f32
    int cnt = 0;
    if (mode == 0) {
        const unsigned char* r = mb + (size_t)b * N;
        for (int i = t; i < N; i += 1024) cnt += (r[i] != 0);
    } else if (mode == 1 || mode == 3) {
        const unsigned int* r = (const unsigned int*)mask + (size_t)b * N;
        for (int i = t; i < N; i += 1024) cnt += (r[i] != 0);
    } else if (mode == 2) {
        const unsigned short* r = (const unsigned short*)mask + (size_t)b * N;
        for (int i = t; i < N; i += 1024) cnt += (r[i] != 0);
    } else {
        const unsigned long long* r = (const unsigned long long*)mask + (size_t)b * N;
        for (int i = t; i < N; i += 1024) cnt += (r[i] != 0ULL);
    }
    for (int o = 32; o > 0; o >>= 1) cnt += __shfl_down(cnt, o);
    if ((t & 63) == 0) s_w[t >> 6] = cnt;
    for (int i = t; i < N; i += 1024) s_cnt[i] = 0;
    __syncthreads();
    if (t == 0) {
        int a = 0;
        for (int i = 0; i < 16; i++) a += s_w[i];
        s_n = a > N ? N : a;
        s_ovf = 0;
    }
    __syncthreads();
    const int n = s_n;
    // --- single edge pass: CSR fill; final s_cnt = full degree ---
    const int4* es4 = (const int4*)(eidx + (size_t)b * 2 * E);
    const int4* ed4 = es4 + E / 4;
    for (int i = t; i < E / 4; i += 1024) {
        int4 s4 = es4[i], d4 = ed4[i];
#define FILL1(SS, DD)                                                          \
        if ((unsigned)(SS) < (unsigned)n && (unsigned)(DD) < (unsigned)n) {    \
            int pos = atomicAdd(&s_cnt[DD], 1);                                \
            if (pos < CAP)                                                     \
                ssrc[((size_t)(bN + (DD))) * CAP + pos] = (unsigned short)(SS);\
            else {                                                             \
                int oi = atomicAdd(&s_ovf, 1);                                 \
                if (oi < E) ovf[(size_t)b * E + oi] = make_int2((DD), (SS));   \
            }                                                                  \
        }
        FILL1(s4.x, d4.x) FILL1(s4.y, d4.y) FILL1(s4.z, d4.z) FILL1(s4.w, d4.w)
#undef FILL1
    }
    __syncthreads();
    for (int v = t; v < N; v += 1024) {
        int c = s_cnt[v];
        dis[bN + v] = (v < n) ? rsqrtf((float)(c + 1)) : 0.0f;
        degc[bN + v] = (unsigned char)(c < CAP ? c : CAP);
    }
    if (t < H) pooled[b * H + t] = 0.0f;
    if (t == 0) { n_arr[b] = n; ovf_cnt[b] = s_ovf; done[b] = 0; }
    // --- cast this batch's x rows to packed bf16 (only needed for f32 x) ---
    if (!s_xbf) {
        const float4* xp = (const float4*)((const float*)x + (size_t)bN * F);
        uint2* yp = (uint2*)(y_u + (size_t)bN * (F / 2));
        for (int i = t; i < N * F / 4; i += 1024) {
            float4 v = xp[i];
            yp[i] = make_uint2(pack2(v.x, v.y), pack2(v.z, v.w));
        }
    }
    // --- weight prep (blocks 1..8; block-uniform path, barriers safe) ---
    if (b >= 1 && b <= 8) {
        int sz;
        switch (b) {
            case 1: sz = F * H; break;
            case 2: sz = H; break;
            case 3: sz = H * H; break;
            case 4: sz = H; break;
            case 5: sz = H * H; break;
            case 6: sz = H; break;
            case 7: sz = H * OUTD; break;
            default: sz = OUTD; break;
        }
        const int K = sz < 1024 ? sz : 1024;
        const unsigned short* p = (const unsigned short*)pa.src[b];
        float s = (t < K) ? fminf(fabsf(b2f(p[t])), 1e6f) : 0.f;
        for (int o = 32; o > 0; o >>= 1) s += __shfl_down(s, o);
        __syncthreads();
        if ((t & 63) == 0) s_fred[t >> 6] = s;
        __syncthreads();
        if (t == 0) {
            float a = 0.f;
            for (int i = 0; i < 16; i++) a += s_fred[i];
            s_pf = (a < 100.0f * (float)K) ? 1 : 0;
        }
        __syncthreads();
        const int fl = s_pf;
        auto rd = [&](int i) -> float {
            return fl ? b2f(((const unsigned short*)pa.src[b])[i])
                      : ((const float*)pa.src[b])[i];
        };
        if (b == 1) {  // W1 (32x64) -> W1T bf16 image, stride 40
            unsigned short* dst = (unsigned short*)pa.dst[b];
            for (int i = t; i < F * H; i += 1024) {
                int k = i >> 6, n2 = i & 63;
                dst[n2 * 40 + k] = f2b(rd(i));
            }
        } else if (b == 3) {  // W2 (64x64) -> W2T bf16 image, stride 72
            unsigned short* dst = (unsigned short*)pa.dst[b];
            for (int i = t; i < H * H; i += 1024) {
                int k = i >> 6, n2 = i & 63;
                dst[n2 * 72 + k] = f2b(rd(i));
            }
        } else {
            float* dst = (float*)pa.dst[b];
            for (int i = t; i < sz; i += 1024) dst[i] = rd(i);
        }
    }
}

// ---------------------------------------------------------------------------
// K2: layer-1 gather (per-node divergent bound, unroll-2, per-edge dis fma)
// + MFMA GEMM1 + relu + dis-premult -> z (bf16). XCD swizzle.
// ---------------------------------------------------------------------------
__global__ __launch_bounds__(256) void k_agg_gemm1(
    const void* __restrict__ x, const unsigned int* __restrict__ y_conv,
    const int* __restrict__ flags, const float* __restrict__ dis,
    const unsigned char* __restrict__ degc, const unsigned short* __restrict__ ssrc,
    const int2* __restrict__ ovf, const int* __restrict__ ovf_cnt,
    const unsigned short* __restrict__ w1t, const float* __restrict__ b1f,
    unsigned short* __restrict__ zs) {
    __shared__ unsigned short s_e[64 * CAP + 32];   // +pad: tail over-read
    __shared__ unsigned char s_dg[64];
    __shared__ float s_dv[64];
    __shared__ float s_b1[64];
    __shared__ __align__(16) unsigned short s_w1t[64 * 40];
    __shared__ __align__(16) unsigned short s_a1[64 * 40];
    const int bid = blockIdx.x;
    const int b = (bid & 7) + ((bid >> 8) << 3);
    const int v0 = ((bid >> 3) & 31) * 64;
    const int t = threadIdx.x;
    const int bN = b * N;
    if (t < 128) ((int4*)s_e)[t] = ((const int4*)(ssrc + (size_t)(bN + v0) * CAP))[t];
    if (t >= 128 && t < 144)
        ((unsigned int*)s_dg)[t - 128] = ((const unsigned int*)(degc + bN + v0))[t - 128];
    if (t >= 192) s_dv[t - 192] = dis[bN + v0 + (t - 192)];
    if (t >= 144 && t < 208) s_b1[t - 144] = b1f[t - 144];
    for (int i = t; i < 320; i += 256) ((int4*)s_w1t)[i] = ((const int4*)w1t)[i];
    __syncthreads();
    const int lane = t & 63;
    const int w = t >> 6;
    const int oc = ovf_cnt[b];
    const unsigned int* yb =
        (flags[0] ? (const unsigned int*)x : y_conv) + (size_t)bN * (F / 2);
    const float* disb = dis + bN;
    {
        const int nn = w * 16 + (lane >> 2);   // node in block
        const int v = v0 + nn;
        const int cu = (lane & 3) * 4;         // uint col base (row = 16 uints)
        const int dg = s_dg[nn];
        const float dv = s_dv[nn];
        const unsigned short* ep = &s_e[nn * CAP];
        float a[8] = {0.f, 0.f, 0.f, 0.f, 0.f, 0.f, 0.f, 0.f};
        uint4 rs = *(const uint4*)(yb + (size_t)v * (F / 2) + cu);   // self
        fma8(a, rs, dv);
        for (int s = 0; s < dg; s += 2) {
            int i0 = ep[s] & (N - 1);
            int i1 = ep[s + 1] & (N - 1);      // tail slot: garbage ok, w1=0
            float w0 = disb[i0];
            float w1 = (s + 1 < dg) ? disb[i1] : 0.f;
            uint4 r0 = *(const uint4*)(yb + (size_t)i0 * (F / 2) + cu);
            uint4 r1 = *(const uint4*)(yb + (size_t)i1 * (F / 2) + cu);
            fma8(a, r0, w0);
            fma8(a, r1, w1);
        }
        if (oc > 0) {  // deg>CAP spills; ~never taken
            const int2* ob = ovf + (size_t)b * E;
            for (int j = 0; j < oc; j++) {
                int2 o = ob[j];
                if (o.x == v) {
                    uint4 u4 = *(const uint4*)(yb + (size_t)o.y * (F / 2) + cu);
                    fma8(a, u4, disb[o.y]);
                }
            }
        }
        uint4 ovv;
        ovv.x = pack2(a[0] * dv, a[1] * dv);
        ovv.y = pack2(a[2] * dv, a[3] * dv);
        ovv.z = pack2(a[4] * dv, a[5] * dv);
        ovv.w = pack2(a[6] * dv, a[7] * dv);
        *(uint4*)((unsigned int*)s_a1 + nn * 20 + cu) = ovv;
    }
    __syncthreads();
    // MFMA GEMM1: wave w -> rows m0..m0+15 of (a1 @ W1)
    const int quad = lane >> 4;
    const int f2 = lane & 15;
    const int m0 = w * 16;
    bf16x8 af = *(const bf16x8*)&s_a1[(m0 + f2) * 40 + quad * 8];
    float dvr[4];
#pragma unroll
    for (int r = 0; r < 4; r++) dvr[r] = s_dv[m0 + quad * 4 + r];
#pragma unroll
    for (int nt = 0; nt < 4; nt++) {
        bf16x8 bf = *(const bf16x8*)&s_w1t[(nt * 16 + f2) * 40 + quad * 8];
        f32x4 acc = {0.f, 0.f, 0.f, 0.f};
        acc = __builtin_amdgcn_mfma_f32_16x16x32_bf16(af, bf, acc, 0, 0, 0);
        float bb = s_b1[nt * 16 + f2];
#pragma unroll
        for (int r = 0; r < 4; r++) {
            int row = m0 + quad * 4 + r;
            float val = dvr[r] * fmaxf(acc[r] + bb, 0.0f);
            zs[(size_t)(bN + v0 + row) * H + nt * 16 + f2] = f2b(val);
        }
    }
}

// ---------------------------------------------------------------------------
// K3: layer-2 gather (per-node divergent bound, unroll-2) + MFMA GEMM2 +
// relu + pool; last block of each batch runs the MLP head (done-counter).
// ---------------------------------------------------------------------------
__global__ __launch_bounds__(256) void k_agg_gemm2_pool(
    const unsigned int* __restrict__ z_u, const float* __restrict__ dis,
    const unsigned char* __restrict__ degc, const unsigned short* __restrict__ ssrc,
    const int2* __restrict__ ovf, const int* __restrict__ ovf_cnt,
    const unsigned short* __restrict__ w2t, const float* __restrict__ b2f_,
    float* __restrict__ pooled, int* __restrict__ done,
    const int* __restrict__ n_arr, const float* __restrict__ aW1,
    const float* __restrict__ ab1, const float* __restrict__ aW2,
    const float* __restrict__ ab2, const int* __restrict__ flags,
    void* __restrict__ out) {
    __shared__ unsigned short s_e[64 * CAP + 32];   // +pad: tail over-read
    __shared__ unsigned char s_dg[64];
    __shared__ float s_dv[64];
    __shared__ float s_b2[64];
    __shared__ __align__(16) unsigned short s_w2t[64 * 72];
    __shared__ __align__(16) unsigned short s_a2[64 * 72];
    __shared__ float s_pool[4][64];
    __shared__ float s_p[64], s_h[64];
    __shared__ int s_last;
    const int bid = blockIdx.x;
    const int b = (bid & 7) + ((bid >> 8) << 3);
    const int v0 = ((bid >> 3) & 31) * 64;
    const int t = threadIdx.x;
    const int bN = b * N;
    if (t < 128) ((int4*)s_e)[t] = ((const int4*)(ssrc + (size_t)(bN + v0) * CAP))[t];
    if (t >= 128 && t < 144)
        ((unsigned int*)s_dg)[t - 128] = ((const unsigned int*)(degc + bN + v0))[t - 128];
    if (t >= 192) s_dv[t - 192] = dis[bN + v0 + (t - 192)];
    if (t >= 144 && t < 208) s_b2[t - 144] = b2f_[t - 144];
    for (int i = t; i < 576; i += 256) ((int4*)s_w2t)[i] = ((const int4*)w2t)[i];
    __syncthreads();
    const int lane = t & 63;
    const int w = t >> 6;
    const int oc = ovf_cnt[b];
    const unsigned int* zb = z_u + (size_t)bN * (H / 2);
#pragma unroll
    for (int g = 0; g < 2; g++) {
        const int nn = w * 16 + g * 8 + (lane >> 3);  // node in block
        const int v = v0 + nn;
        const int cu = (lane & 7) * 4;                // uint col base (row = 32 uints)
        const int dg = s_dg[nn];
        const unsigned short* ep = &s_e[nn * CAP];
        float a[8] = {0.f, 0.f, 0.f, 0.f, 0.f, 0.f, 0.f, 0.f};
        uint4 rs = *(const uint4*)(zb + (size_t)v * (H / 2) + cu);   // self
        add8(a, rs);
        for (int s = 0; s < dg; s += 2) {
            int i0 = ep[s] & (N - 1);
            int i1 = ep[s + 1] & (N - 1);      // tail slot: garbage ok, w1=0
            float w1 = (s + 1 < dg) ? 1.0f : 0.f;
            uint4 r0 = *(const uint4*)(zb + (size_t)i0 * (H / 2) + cu);
            uint4 r1 = *(const uint4*)(zb + (size_t)i1 * (H / 2) + cu);
            add8(a, r0);
            fma8(a, r1, w1);
        }
        if (oc > 0) {
            const int2* ob = ovf + (size_t)b * E;
            for (int j = 0; j < oc; j++) {
                int2 o = ob[j];
                if (o.x == v) {
                    uint4 u4 = *(const uint4*)(zb + (size_t)o.y * (H / 2) + cu);
                    add8(a, u4);
                }
            }
        }
        const float dv = s_dv[nn];
        uint4 ovv;
        ovv.x = pack2(a[0] * dv, a[1] * dv);
        ovv.y = pack2(a[2] * dv, a[3] * dv);
        ovv.z = pack2(a[4] * dv, a[5] * dv);
        ovv.w = pack2(a[6] * dv, a[7] * dv);
        *(uint4*)((unsigned int*)s_a2 + nn * 36 + cu) = ovv;
    }
    __syncthreads();
    // MFMA GEMM2 + pool
    const int quad = lane >> 4;
    const int f2 = lane & 15;
    const int m0 = w * 16;
    bf16x8 af0 = *(const bf16x8*)&s_a2[(m0 + f2) * 72 + quad * 8];
    bf16x8 af1 = *(const bf16x8*)&s_a2[(m0 + f2) * 72 + 32 + quad * 8];
    float dvr[4];
#pragma unroll
    for (int r = 0; r < 4; r++) dvr[r] = s_dv[m0 + quad * 4 + r];
#pragma unroll
    for (int nt = 0; nt < 4; nt++) {
        bf16x8 bf0 = *(const bf16x8*)&s_w2t[(nt * 16 + f2) * 72 + quad * 8];
        bf16x8 bf1 = *(const bf16x8*)&s_w2t[(nt * 16 + f2) * 72 + 32 + quad * 8];
        f32x4 acc = {0.f, 0.f, 0.f, 0.f};
        acc = __builtin_amdgcn_mfma_f32_16x16x32_bf16(af0, bf0, acc, 0, 0, 0);
        acc = __builtin_amdgcn_mfma_f32_16x16x32_bf16(af1, bf1, acc, 0, 0, 0);
        float bb = s_b2[nt * 16 + f2];
        float ps = 0.f;
#pragma unroll
        for (int r = 0; r < 4; r++)
            ps += (dvr[r] > 0.0f) ? fmaxf(acc[r] + bb, 0.0f) : 0.0f;
        ps += __shfl_xor(ps, 16);
        ps += __shfl_xor(ps, 32);
        if (quad == 0) s_pool[w][nt * 16 + f2] = ps;
    }
    __syncthreads();
    if (t < H)
        atomicAdd(&pooled[b * H + t],
                  s_pool[0][t] + s_pool[1][t] + s_pool[2][t] + s_pool[3][t]);
    __syncthreads();   // drains this block's pooled atomics (vmcnt 0 @ barrier)
    __threadfence();
    if (t == 0) s_last = (atomicAdd(&done[b], 1) == 31) ? 1 : 0;
    __syncthreads();
    if (s_last && t < 64) {   // wave 0 of last block: MLP head
        float pv = atomicAdd(&pooled[b * H + t], 0.0f);   // coherent read
        int n = n_arr[b];
        if (n < 1) n = 1;
        s_p[t] = pv / (float)n;
        float acc = ab1[t];
        for (int j = 0; j < 64; j++) acc += s_p[j] * aW1[j * 64 + t];
        s_h[t] = fmaxf(acc, 0.0f);
        if (t < 16) {
            float a2 = ab2[t];
            for (int j = 0; j < 64; j++) a2 += s_h[j] * aW2[j * 16 + t];
            if (flags[0]) ((unsigned short*)out)[b * OUTD + t] = f2b(a2);
            else          ((float*)out)[b * OUTD + t] = a2;
        }
    }
}

// ---------------------------------------------------------------------------
extern "C" void kernel_launch(void* const* d_in, const int* in_sizes, int n_in,
                              void* d_out, int out_size, void* d_ws, size_t ws_size,
                              hipStream_t stream) {
    const void* x    = d_in[0];
    const int*  eidx = (const int*)d_in[1];
    const void* mask = d_in[2];

    char* ws = (char*)d_ws;
    size_t off = 0;
    auto alloc = [&](size_t bytes) -> void* {
        void* p = ws + off;
        off += (bytes + 255) & ~(size_t)255;
        return p;
    };
    int*   flags   = (int*)alloc(16 * sizeof(int));
    unsigned short* w1t = (unsigned short*)alloc(64 * 40 * 2);
    unsigned short* w2t = (unsigned short*)alloc(64 * 72 * 2);
    float* b1f     = (float*)alloc(H * sizeof(float));
    float* b2f_    = (float*)alloc(H * sizeof(float));
    float* aW1f    = (float*)alloc(H * H * sizeof(float));
    float* ab1f    = (float*)alloc(H * sizeof(float));
    float* aW2f    = (float*)alloc(H * OUTD * sizeof(float));
    float* ab2f    = (float*)alloc(OUTD * sizeof(float));
    int*   n_arr   = (int*)alloc(B * sizeof(int));
    int*   done    = (int*)alloc(B * sizeof(int));
    float* dis     = (float*)alloc((size_t)B * N * sizeof(float));
    unsigned char*  degc = (unsigned char*)alloc((size_t)B * N);
    unsigned short* ssrc = (unsigned short*)alloc((size_t)B * N * CAP * 2);
    int2*  ovf     = (int2*)alloc((size_t)B * E * sizeof(int2));
    int*   ovf_cnt = (int*)alloc(B * sizeof(int));
    float* pooled  = (float*)alloc((size_t)B * H * sizeof(float));
    unsigned int* y_u = (unsigned int*)alloc((size_t)B * N * (F / 2) * 4);
    unsigned int* z_u = (unsigned int*)alloc((size_t)B * N * (H / 2) * 4);

    PrepArgs pa;
    pa.src[0] = x;        pa.dst[0] = pooled;  // dst[0] unused
    pa.src[1] = d_in[3];  pa.dst[1] = w1t;
    pa.src[2] = d_in[4];  pa.dst[2] = b1f;
    pa.src[3] = d_in[5];  pa.dst[3] = w2t;
    pa.src[4] = d_in[6];  pa.dst[4] = b2f_;
    pa.src[5] = d_in[7];  pa.dst[5] = aW1f;
    pa.src[6] = d_in[8];  pa.dst[6] = ab1f;
    pa.src[7] = d_in[9];  pa.dst[7] = aW2f;
    pa.src[8] = d_in[10]; pa.dst[8] = ab2f;

    // build + prep fused (single pass over edges; casts x if f32)
    k_build<<<B, 1024, 0, stream>>>(x, eidx, mask, pa, flags, n_arr, dis, degc,
                                    ssrc, ovf, ovf_cnt, pooled, done, y_u);
    // a1 = dis_v*(dis_v*x[v]+sum dis_s*x[s]); z = dis*relu(a1@W1+b1)  [MFMA]
    k_agg_gemm1<<<B * 32, 256, 0, stream>>>(x, y_u, flags, dis, degc, ssrc, ovf,
                                            ovf_cnt, w1t, b1f,
                                            (unsigned short*)z_u);
    // a2 = dis*(z[v]+sum z[s]); h2 = relu(a2@W2+b2); pool; last block: MLP
    k_agg_gemm2_pool<<<B * 32, 256, 0, stream>>>(z_u, dis, degc, ssrc, ovf,
                                                 ovf_cnt, w2t, b2f_, pooled,
                                                 done, n_arr, aW1f, ab1f, aW2f,
                                                 ab2f, flags, d_out);
}

// Round 4
// 164.415 us; speedup vs baseline: 2.8500x; 2.8500x over previous
//
#include <hip/hip_runtime.h>
#include <hip/hip_bf16.h>

#define B 128
#define N 2048
#define E 16384
#define F 32
#define H 64
#define OUTD 16
#define CAP 16
#define NP1 (N + 1)

typedef __attribute__((ext_vector_type(8))) short bf16x8;
typedef __attribute__((ext_vector_type(4))) float f32x4;

__device__ __forceinline__ float b2f(unsigned short u) {
    return __uint_as_float(((unsigned int)u) << 16);
}
__device__ __forceinline__ unsigned short f2b(float f) {
    unsigned int x = __float_as_uint(f);
    unsigned int r = (x + 0x7FFFu + ((x >> 16) & 1u)) >> 16;  // RNE, finite
    return (unsigned short)r;
}
__device__ __forceinline__ unsigned int pack2(float a, float b) {
    return (unsigned int)f2b(a) | ((unsigned int)f2b(b) << 16);
}

// unpack 4 packed-bf16-pair uints into 8 f32 accumulators
__device__ __forceinline__ void unpack8(float (&a)[8], uint4 u) {
    a[0] += __uint_as_float(u.x << 16);
    a[1] += __uint_as_float(u.x & 0xffff0000u);
    a[2] += __uint_as_float(u.y << 16);
    a[3] += __uint_as_float(u.y & 0xffff0000u);
    a[4] += __uint_as_float(u.z << 16);
    a[5] += __uint_as_float(u.z & 0xffff0000u);
    a[6] += __uint_as_float(u.w << 16);
    a[7] += __uint_as_float(u.w & 0xffff0000u);
}

struct PrepArgs {
    const void* src[9];
    void* dst[9];
};

// ---------------------------------------------------------------------------
// K1: fused build. One block of 1024 threads per batch:
//   - probe x dtype; mask count -> n
//   - sentinel-init ssrc (=N); zero y/z row N (stride N+1 images)
//   - SINGLE edge pass: CSR fill (final LDS counter = full degree)
//   - dis/degc; premult y = dis * x (packed bf16; dv recomputed from LDS)
//   - blocks 1..8: weight prep (W1T/W2T bf16 images, f32 copies of rest)
// NOTE (R3 lesson): no __threadfence, no divergent gather loops here.
// ---------------------------------------------------------------------------
__global__ __launch_bounds__(1024) void k_build(
    const void* __restrict__ x, const int* __restrict__ eidx,
    const void* __restrict__ mask, PrepArgs pa, int* __restrict__ flags,
    int* __restrict__ n_arr, float* __restrict__ dis,
    unsigned char* __restrict__ degc, unsigned short* __restrict__ ssrc,
    int2* __restrict__ ovf, int* __restrict__ ovf_cnt,
    float* __restrict__ pooled, unsigned int* __restrict__ y_u,
    unsigned int* __restrict__ z_u) {
    __shared__ int s_cnt[N];
    __shared__ float s_fred[16];
    __shared__ int s_w[16];
    __shared__ int s_n, s_ovf, s_xbf, s_pf;
    const int b = blockIdx.x;
    const int t = threadIdx.x;
    const int bN = b * N;
    // --- probe x dtype (first 1024 bf16-interpreted elems) ---
    {
        const unsigned short* p = (const unsigned short*)x;
        float s = fminf(fabsf(b2f(p[t])), 1e6f);
        for (int o = 32; o > 0; o >>= 1) s += __shfl_down(s, o);
        if ((t & 63) == 0) s_fred[t >> 6] = s;
        __syncthreads();
        if (t == 0) {
            float a = 0.f;
            for (int i = 0; i < 16; i++) a += s_fred[i];
            int f = (a < 100.0f * 1024.0f) ? 1 : 0;
            s_xbf = f;
            if (b == 0) flags[0] = f;
        }
    }
    // --- mask mode + count ---
    const unsigned char* mb = (const unsigned char*)mask;
    int mode;
    if (mb[0] == 0x80 && mb[1] == 0x3F) mode = 2;        // bf16
    else if (mb[0] != 0 && mb[1] != 0) mode = 0;         // bytes
    else if (mb[0] != 0) mode = (mb[4] != 0) ? 1 : 4;    // int32 : int64
    else mode = 3;                                       // f32
    int cnt = 0;
    if (mode == 0) {
        const unsigned char* r = mb + (size_t)b * N;
        for (int i = t; i < N; i += 1024) cnt += (r[i] != 0);
    } else if (mode == 1 || mode == 3) {
        const unsigned int* r = (const unsigned int*)mask + (size_t)b * N;
        for (int i = t; i < N; i += 1024) cnt += (r[i] != 0);
    } else if (mode == 2) {
        const unsigned short* r = (const unsigned short*)mask + (size_t)b * N;
        for (int i = t; i < N; i += 1024) cnt += (r[i] != 0);
    } else {
        const unsigned long long* r = (const unsigned long long*)mask + (size_t)b * N;
        for (int i = t; i < N; i += 1024) cnt += (r[i] != 0ULL);
    }
    for (int o = 32; o > 0; o >>= 1) cnt += __shfl_down(cnt, o);
    if ((t & 63) == 0) s_w[t >> 6] = cnt;
    for (int i = t; i < N; i += 1024) s_cnt[i] = 0;
    // sentinel-init ssrc slots to N (zero-row); overwritten for slots < deg
    {
        const int4 iv = make_int4(0x08000800, 0x08000800, 0x08000800, 0x08000800);
        int4* sp4 = (int4*)(ssrc + (size_t)bN * CAP);
        for (int i = t; i < N * CAP / 8; i += 1024) sp4[i] = iv;
    }
    // zero rows (row index N) of y_u / z_u for this batch
    if (t < 16) y_u[((size_t)b * NP1 + N) * (F / 2) + t] = 0u;
    if (t >= 32 && t < 64) z_u[((size_t)b * NP1 + N) * (H / 2) + (t - 32)] = 0u;
    if (t == 0) s_ovf = 0;
    __syncthreads();
    if (t == 0) {
        int a = 0;
        for (int i = 0; i < 16; i++) a += s_w[i];
        s_n = a > N ? N : a;
    }
    __syncthreads();
    const int n = s_n;
    // --- single edge pass: CSR fill; final s_cnt = full degree ---
    const int4* es4 = (const int4*)(eidx + (size_t)b * 2 * E);
    const int4* ed4 = es4 + E / 4;
    for (int i = t; i < E / 4; i += 1024) {
        int4 s4 = es4[i], d4 = ed4[i];
#define FILL1(SS, DD)                                                          \
        if ((unsigned)(SS) < (unsigned)n && (unsigned)(DD) < (unsigned)n) {    \
            int pos = atomicAdd(&s_cnt[DD], 1);                                \
            if (pos < CAP)                                                     \
                ssrc[((size_t)(bN + (DD))) * CAP + pos] = (unsigned short)(SS);\
            else {                                                             \
                int oi = atomicAdd(&s_ovf, 1);                                 \
                if (oi < E) ovf[(size_t)b * E + oi] = make_int2((DD), (SS));   \
            }                                                                  \
        }
        FILL1(s4.x, d4.x) FILL1(s4.y, d4.y) FILL1(s4.z, d4.z) FILL1(s4.w, d4.w)
#undef FILL1
    }
    __syncthreads();
    for (int v = t; v < N; v += 1024) {
        int c = s_cnt[v];
        dis[bN + v] = (v < n) ? rsqrtf((float)(c + 1)) : 0.0f;
        degc[bN + v] = (unsigned char)(c < CAP ? c : CAP);
    }
    if (t < H) pooled[b * H + t] = 0.0f;
    if (t == 0) { n_arr[b] = n; ovf_cnt[b] = s_ovf; }
    // --- premult: y = dis * x, packed bf16 (dv recomputed from s_cnt) ---
    if (s_xbf) {
        const uint4* xp = (const uint4*)((const unsigned short*)x + (size_t)bN * F);
        for (int i = t; i < N * 4; i += 1024) {     // i: 8-elem chunk
            const int v = i >> 2;
            const int c = s_cnt[v];
            const float dv = (v < n) ? rsqrtf((float)(c + 1)) : 0.0f;
            uint4 u = xp[i];
            uint4 o;
            o.x = pack2(b2f((unsigned short)u.x) * dv, b2f((unsigned short)(u.x >> 16)) * dv);
            o.y = pack2(b2f((unsigned short)u.y) * dv, b2f((unsigned short)(u.y >> 16)) * dv);
            o.z = pack2(b2f((unsigned short)u.z) * dv, b2f((unsigned short)(u.z >> 16)) * dv);
            o.w = pack2(b2f((unsigned short)u.w) * dv, b2f((unsigned short)(u.w >> 16)) * dv);
            *(uint4*)(y_u + ((size_t)b * NP1 + v) * (F / 2) + (i & 3) * 4) = o;
        }
    } else {
        const float4* xp = (const float4*)((const float*)x + (size_t)bN * F);
        for (int i = t; i < N * 4; i += 1024) {     // i: 8-elem chunk
            const int v = i >> 2;
            const int c = s_cnt[v];
            const float dv = (v < n) ? rsqrtf((float)(c + 1)) : 0.0f;
            float4 v1 = xp[i * 2], v2 = xp[i * 2 + 1];
            uint4 o;
            o.x = pack2(v1.x * dv, v1.y * dv);
            o.y = pack2(v1.z * dv, v1.w * dv);
            o.z = pack2(v2.x * dv, v2.y * dv);
            o.w = pack2(v2.z * dv, v2.w * dv);
            *(uint4*)(y_u + ((size_t)b * NP1 + v) * (F / 2) + (i & 3) * 4) = o;
        }
    }
    // --- weight prep (blocks 1..8; block-uniform condition, barriers safe) ---
    if (b >= 1 && b <= 8) {
        int sz;
        switch (b) {
            case 1: sz = F * H; break;
            case 2: sz = H; break;
            case 3: sz = H * H; break;
            case 4: sz = H; break;
            case 5: sz = H * H; break;
            case 6: sz = H; break;
            case 7: sz = H * OUTD; break;
            default: sz = OUTD; break;
        }
        const int K = sz < 1024 ? sz : 1024;
        const unsigned short* p = (const unsigned short*)pa.src[b];
        float s = (t < K) ? fminf(fabsf(b2f(p[t])), 1e6f) : 0.f;
        for (int o = 32; o > 0; o >>= 1) s += __shfl_down(s, o);
        __syncthreads();
        if ((t & 63) == 0) s_fred[t >> 6] = s;
        __syncthreads();
        if (t == 0) {
            float a = 0.f;
            for (int i = 0; i < 16; i++) a += s_fred[i];
            s_pf = (a < 100.0f * (float)K) ? 1 : 0;
        }
        __syncthreads();
        const int fl = s_pf;
        auto rd = [&](int i) -> float {
            return fl ? b2f(((const unsigned short*)pa.src[b])[i])
                      : ((const float*)pa.src[b])[i];
        };
        if (b == 1) {  // W1 (32x64) -> W1T bf16 image, stride 40
            unsigned short* dst = (unsigned short*)pa.dst[b];
            for (int i = t; i < F * H; i += 1024) {
                int k = i >> 6, n2 = i & 63;
                dst[n2 * 40 + k] = f2b(rd(i));
            }
        } else if (b == 3) {  // W2 (64x64) -> W2T bf16 image, stride 72
            unsigned short* dst = (unsigned short*)pa.dst[b];
            for (int i = t; i < H * H; i += 1024) {
                int k = i >> 6, n2 = i & 63;
                dst[n2 * 72 + k] = f2b(rd(i));
            }
        } else {
            float* dst = (float*)pa.dst[b];
            for (int i = t; i < sz; i += 1024) dst[i] = rd(i);
        }
    }
}

// ---------------------------------------------------------------------------
// K2: layer-1 gather: 16 nodes/wave, 4 lanes/node, dwordx4 rows, zero-row
// sentinel (no predication), wave-uniform md, depth-2 pipelined. + MFMA
// GEMM1 + relu + dis-premult -> z (bf16, stride N+1). XCD swizzle.
// ---------------------------------------------------------------------------
__global__ __launch_bounds__(256) void k_agg_gemm1(
    const unsigned int* __restrict__ y_u, const float* __restrict__ dis,
    const unsigned char* __restrict__ degc, const unsigned short* __restrict__ ssrc,
    const int2* __restrict__ ovf, const int* __restrict__ ovf_cnt,
    const unsigned short* __restrict__ w1t, const float* __restrict__ b1f,
    unsigned short* __restrict__ zs) {
    __shared__ unsigned short s_e[64 * CAP];
    __shared__ unsigned char s_dg[64];
    __shared__ float s_dv[64];
    __shared__ float s_b1[64];
    __shared__ __align__(16) unsigned short s_w1t[64 * 40];
    __shared__ __align__(16) unsigned short s_a1[64 * 40];
    const int bid = blockIdx.x;
    const int b = (bid & 7) + ((bid >> 8) << 3);
    const int v0 = ((bid >> 3) & 31) * 64;
    const int t = threadIdx.x;
    const int bN = b * N;
    if (t < 128) ((int4*)s_e)[t] = ((const int4*)(ssrc + (size_t)(bN + v0) * CAP))[t];
    if (t >= 128 && t < 144)
        ((unsigned int*)s_dg)[t - 128] = ((const unsigned int*)(degc + bN + v0))[t - 128];
    if (t >= 192) s_dv[t - 192] = dis[bN + v0 + (t - 192)];
    if (t >= 144 && t < 208) s_b1[t - 144] = b1f[t - 144];
    for (int i = t; i < 320; i += 256) ((int4*)s_w1t)[i] = ((const int4*)w1t)[i];
    __syncthreads();
    const int lane = t & 63;
    const int w = t >> 6;
    const int oc = ovf_cnt[b];
    const unsigned int* yb = y_u + (size_t)b * NP1 * (F / 2);
    {
        const int nn = w * 16 + (lane >> 2);   // node in block
        const int v = v0 + nn;
        const int cu = (lane & 3) * 4;         // uint col base (row = 16 uints)
        // wave-uniform max degree over this wave's 16 nodes
        int md = s_dg[w * 16 + (lane & 15)];
        int m2;
        m2 = __shfl_xor(md, 1); md = md > m2 ? md : m2;
        m2 = __shfl_xor(md, 2); md = md > m2 ? md : m2;
        m2 = __shfl_xor(md, 4); md = md > m2 ? md : m2;
        m2 = __shfl_xor(md, 8); md = md > m2 ? md : m2;
        const unsigned short* ep = &s_e[nn * CAP];
        float a[8] = {0.f, 0.f, 0.f, 0.f, 0.f, 0.f, 0.f, 0.f};
        uint4 cur = *(const uint4*)(yb + (size_t)v * (F / 2) + cu);      // self
        uint4 nxt = *(const uint4*)(yb + (size_t)ep[0] * (F / 2) + cu);
        for (int s = 0; s < md; s++) {
            int sn = s + 1; sn = sn > CAP - 1 ? CAP - 1 : sn;
            uint4 n2 = *(const uint4*)(yb + (size_t)ep[sn] * (F / 2) + cu);
            unpack8(a, cur);
            cur = nxt; nxt = n2;
        }
        unpack8(a, cur);
        if (oc > 0) {  // deg>CAP spills; ~never taken
            const int2* ob = ovf + (size_t)b * E;
            for (int j = 0; j < oc; j++) {
                int2 o = ob[j];
                if (o.x == v) {
                    uint4 u4 = *(const uint4*)(yb + (size_t)o.y * (F / 2) + cu);
                    unpack8(a, u4);
                }
            }
        }
        const float dv = s_dv[nn];
        uint4 ov;
        ov.x = pack2(a[0] * dv, a[1] * dv);
        ov.y = pack2(a[2] * dv, a[3] * dv);
        ov.z = pack2(a[4] * dv, a[5] * dv);
        ov.w = pack2(a[6] * dv, a[7] * dv);
        *(uint4*)((unsigned int*)s_a1 + nn * 20 + cu) = ov;
    }
    __syncthreads();
    // MFMA GEMM1: wave w -> rows m0..m0+15 of (a1 @ W1)
    const int quad = lane >> 4;
    const int f2 = lane & 15;
    const int m0 = w * 16;
    bf16x8 af = *(const bf16x8*)&s_a1[(m0 + f2) * 40 + quad * 8];
    float dvr[4];
#pragma unroll
    for (int r = 0; r < 4; r++) dvr[r] = s_dv[m0 + quad * 4 + r];
#pragma unroll
    for (int nt = 0; nt < 4; nt++) {
        bf16x8 bf = *(const bf16x8*)&s_w1t[(nt * 16 + f2) * 40 + quad * 8];
        f32x4 acc = {0.f, 0.f, 0.f, 0.f};
        acc = __builtin_amdgcn_mfma_f32_16x16x32_bf16(af, bf, acc, 0, 0, 0);
        float bb = s_b1[nt * 16 + f2];
#pragma unroll
        for (int r = 0; r < 4; r++) {
            int row = m0 + quad * 4 + r;
            float val = dvr[r] * fmaxf(acc[r] + bb, 0.0f);
            zs[((size_t)b * NP1 + v0 + row) * H + nt * 16 + f2] = f2b(val);
        }
    }
}

// ---------------------------------------------------------------------------
// K3: layer-2 gather: 2 groups of 8 nodes/wave, 8 lanes/node, dwordx4 rows,
// zero-row sentinel, wave-uniform md, depth-2 pipelined. + MFMA GEMM2 +
// relu + pool.
// ---------------------------------------------------------------------------
__global__ __launch_bounds__(256) void k_agg_gemm2_pool(
    const unsigned int* __restrict__ z_u, const float* __restrict__ dis,
    const unsigned char* __restrict__ degc, const unsigned short* __restrict__ ssrc,
    const int2* __restrict__ ovf, const int* __restrict__ ovf_cnt,
    const unsigned short* __restrict__ w2t, const float* __restrict__ b2f_,
    float* __restrict__ pooled) {
    __shared__ unsigned short s_e[64 * CAP];
    __shared__ unsigned char s_dg[64];
    __shared__ float s_dv[64];
    __shared__ float s_b2[64];
    __shared__ __align__(16) unsigned short s_w2t[64 * 72];
    __shared__ __align__(16) unsigned short s_a2[64 * 72];
    __shared__ float s_pool[4][64];
    const int bid = blockIdx.x;
    const int b = (bid & 7) + ((bid >> 8) << 3);
    const int v0 = ((bid >> 3) & 31) * 64;
    const int t = threadIdx.x;
    const int bN = b * N;
    if (t < 128) ((int4*)s_e)[t] = ((const int4*)(ssrc + (size_t)(bN + v0) * CAP))[t];
    if (t >= 128 && t < 144)
        ((unsigned int*)s_dg)[t - 128] = ((const unsigned int*)(degc + bN + v0))[t - 128];
    if (t >= 192) s_dv[t - 192] = dis[bN + v0 + (t - 192)];
    if (t >= 144 && t < 208) s_b2[t - 144] = b2f_[t - 144];
    for (int i = t; i < 576; i += 256) ((int4*)s_w2t)[i] = ((const int4*)w2t)[i];
    __syncthreads();
    const int lane = t & 63;
    const int w = t >> 6;
    const int oc = ovf_cnt[b];
    const unsigned int* zb = z_u + (size_t)b * NP1 * (H / 2);
#pragma unroll
    for (int g = 0; g < 2; g++) {
        const int nn = w * 16 + g * 8 + (lane >> 3);  // node in block
        const int v = v0 + nn;
        const int cu = (lane & 7) * 4;                // uint col base (row = 32 uints)
        int md = s_dg[w * 16 + g * 8 + (lane & 7)];
        int m2;
        m2 = __shfl_xor(md, 1); md = md > m2 ? md : m2;
        m2 = __shfl_xor(md, 2); md = md > m2 ? md : m2;
        m2 = __shfl_xor(md, 4); md = md > m2 ? md : m2;
        const unsigned short* ep = &s_e[nn * CAP];
        float a[8] = {0.f, 0.f, 0.f, 0.f, 0.f, 0.f, 0.f, 0.f};
        uint4 cur = *(const uint4*)(zb + (size_t)v * (H / 2) + cu);      // self
        uint4 nxt = *(const uint4*)(zb + (size_t)ep[0] * (H / 2) + cu);
        for (int s = 0; s < md; s++) {
            int sn = s + 1; sn = sn > CAP - 1 ? CAP - 1 : sn;
            uint4 n2 = *(const uint4*)(zb + (size_t)ep[sn] * (H / 2) + cu);
            unpack8(a, cur);
            cur = nxt; nxt = n2;
        }
        unpack8(a, cur);
        if (oc > 0) {
            const int2* ob = ovf + (size_t)b * E;
            for (int j = 0; j < oc; j++) {
                int2 o = ob[j];
                if (o.x == v) {
                    uint4 u4 = *(const uint4*)(zb + (size_t)o.y * (H / 2) + cu);
                    unpack8(a, u4);
                }
            }
        }
        const float dv = s_dv[nn];
        uint4 ov;
        ov.x = pack2(a[0] * dv, a[1] * dv);
        ov.y = pack2(a[2] * dv, a[3] * dv);
        ov.z = pack2(a[4] * dv, a[5] * dv);
        ov.w = pack2(a[6] * dv, a[7] * dv);
        *(uint4*)((unsigned int*)s_a2 + nn * 36 + cu) = ov;
    }
    __syncthreads();
    // MFMA GEMM2 + pool
    const int quad = lane >> 4;
    const int f2 = lane & 15;
    const int m0 = w * 16;
    bf16x8 af0 = *(const bf16x8*)&s_a2[(m0 + f2) * 72 + quad * 8];
    bf16x8 af1 = *(const bf16x8*)&s_a2[(m0 + f2) * 72 + 32 + quad * 8];
    float dvr[4];
#pragma unroll
    for (int r = 0; r < 4; r++) dvr[r] = s_dv[m0 + quad * 4 + r];
#pragma unroll
    for (int nt = 0; nt < 4; nt++) {
        bf16x8 bf0 = *(const bf16x8*)&s_w2t[(nt * 16 + f2) * 72 + quad * 8];
        bf16x8 bf1 = *(const bf16x8*)&s_w2t[(nt * 16 + f2) * 72 + 32 + quad * 8];
        f32x4 acc = {0.f, 0.f, 0.f, 0.f};
        acc = __builtin_amdgcn_mfma_f32_16x16x32_bf16(af0, bf0, acc, 0, 0, 0);
        acc = __builtin_amdgcn_mfma_f32_16x16x32_bf16(af1, bf1, acc, 0, 0, 0);
        float bb = s_b2[nt * 16 + f2];
        float ps = 0.f;
#pragma unroll
        for (int r = 0; r < 4; r++)
            ps += (dvr[r] > 0.0f) ? fmaxf(acc[r] + bb, 0.0f) : 0.0f;
        ps += __shfl_xor(ps, 16);
        ps += __shfl_xor(ps, 32);
        if (quad == 0) s_pool[w][nt * 16 + f2] = ps;
    }
    __syncthreads();
    if (t < H)
        atomicAdd(&pooled[b * H + t],
                  s_pool[0][t] + s_pool[1][t] + s_pool[2][t] + s_pool[3][t]);
}

// ---------------------------------------------------------------------------
// K4: MLP head, one wave per batch.
// ---------------------------------------------------------------------------
__global__ __launch_bounds__(64) void k_mlp(
    const float* __restrict__ pooled, const int* __restrict__ n_arr,
    const float* __restrict__ aW1, const float* __restrict__ ab1,
    const float* __restrict__ aW2, const float* __restrict__ ab2,
    const int* __restrict__ flags, void* __restrict__ out) {
    const int b = blockIdx.x;
    const int t = threadIdx.x;
    __shared__ float p[64];
    __shared__ float hid[64];
    int n = n_arr[b];
    if (n < 1) n = 1;
    p[t] = pooled[b * H + t] / (float)n;
    __syncthreads();
    float acc = ab1[t];
    for (int j = 0; j < 64; j++) acc += p[j] * aW1[j * 64 + t];
    hid[t] = fmaxf(acc, 0.0f);
    __syncthreads();
    if (t < 16) {
        float a2 = ab2[t];
        for (int j = 0; j < 64; j++) a2 += hid[j] * aW2[j * 16 + t];
        if (flags[0]) ((unsigned short*)out)[b * OUTD + t] = f2b(a2);
        else          ((float*)out)[b * OUTD + t] = a2;
    }
}

// ---------------------------------------------------------------------------
extern "C" void kernel_launch(void* const* d_in, const int* in_sizes, int n_in,
                              void* d_out, int out_size, void* d_ws, size_t ws_size,
                              hipStream_t stream) {
    const void* x    = d_in[0];
    const int*  eidx = (const int*)d_in[1];
    const void* mask = d_in[2];

    char* ws = (char*)d_ws;
    size_t off = 0;
    auto alloc = [&](size_t bytes) -> void* {
        void* p = ws + off;
        off += (bytes + 255) & ~(size_t)255;
        return p;
    };
    int*   flags   = (int*)alloc(16 * sizeof(int));
    unsigned short* w1t = (unsigned short*)alloc(64 * 40 * 2);
    unsigned short* w2t = (unsigned short*)alloc(64 * 72 * 2);
    float* b1f     = (float*)alloc(H * sizeof(float));
    float* b2f_    = (float*)alloc(H * sizeof(float));
    float* aW1f    = (float*)alloc(H * H * sizeof(float));
    float* ab1f    = (float*)alloc(H * sizeof(float));
    float* aW2f    = (float*)alloc(H * OUTD * sizeof(float));
    float* ab2f    = (float*)alloc(OUTD * sizeof(float));
    int*   n_arr   = (int*)alloc(B * sizeof(int));
    float* dis     = (float*)alloc((size_t)B * N * sizeof(float));
    unsigned char*  degc = (unsigned char*)alloc((size_t)B * N);
    unsigned short* ssrc = (unsigned short*)alloc((size_t)B * N * CAP * 2);
    int2*  ovf     = (int2*)alloc((size_t)B * E * sizeof(int2));
    int*   ovf_cnt = (int*)alloc(B * sizeof(int));
    float* pooled  = (float*)alloc((size_t)B * H * sizeof(float));
    unsigned int* y_u = (unsigned int*)alloc((size_t)B * NP1 * (F / 2) * 4);
    unsigned int* z_u = (unsigned int*)alloc((size_t)B * NP1 * (H / 2) * 4);

    PrepArgs pa;
    pa.src[0] = x;        pa.dst[0] = pooled;  // dst[0] unused
    pa.src[1] = d_in[3];  pa.dst[1] = w1t;
    pa.src[2] = d_in[4];  pa.dst[2] = b1f;
    pa.src[3] = d_in[5];  pa.dst[3] = w2t;
    pa.src[4] = d_in[6];  pa.dst[4] = b2f_;
    pa.src[5] = d_in[7];  pa.dst[5] = aW1f;
    pa.src[6] = d_in[8];  pa.dst[6] = ab1f;
    pa.src[7] = d_in[9];  pa.dst[7] = aW2f;
    pa.src[8] = d_in[10]; pa.dst[8] = ab2f;

    // build + prep + premult fused (single edge pass; y = dis*x packed bf16)
    k_build<<<B, 1024, 0, stream>>>(x, eidx, mask, pa, flags, n_arr, dis, degc,
                                    ssrc, ovf, ovf_cnt, pooled, y_u, z_u);
    // a1 = dis*(y[v]+sum y[s]); z = dis * relu(a1@W1 + b1)   [MFMA]
    k_agg_gemm1<<<B * 32, 256, 0, stream>>>(y_u, dis, degc, ssrc, ovf, ovf_cnt,
                                            w1t, b1f, (unsigned short*)z_u);
    // a2 = dis*(z[v]+sum z[s]); h2 = relu(a2@W2 + b2); pool  [MFMA]
    k_agg_gemm2_pool<<<B * 32, 256, 0, stream>>>(z_u, dis, degc, ssrc, ovf,
                                                 ovf_cnt, w2t, b2f_, pooled);
    // Head
    k_mlp<<<B, 64, 0, stream>>>(pooled, n_arr, aW1f, ab1f, aW2f, ab2f, flags, d_out);
}